// Round 1
// baseline (16590.508 us; speedup 1.0000x reference)
//
#include <hip/hip_runtime.h>

#define A_GELU 0.7978845608028654f
#define W2S 68    // padded stride (floats) for sW2 [256][68]
#define X2S 260   // padded stride for sX2/sX2b [16][260]
#define XTS 20    // padded stride for sxkT/sxqT [64][20]

__device__ __forceinline__ float fast_tanh(float u){
    float e = __expf(2.0f*u);
    return 1.0f - 2.0f/(e + 1.0f);
}
__device__ __forceinline__ float gelu_f(float x){
    float t = fast_tanh(A_GELU*(x + 0.044715f*x*x*x));
    return 0.5f*x*(1.0f+t);
}
__device__ __forceinline__ float dgelu_f(float x){
    float x2 = x*x;
    float t = fast_tanh(A_GELU*x*(1.0f + 0.044715f*x2));
    return 0.5f*x*((1.0f-t*t)*(A_GELU + 0.1070322243f*x2)) + 0.5f*(1.0f+t);
}

// smem floats: 256*68 + 2*16*260 + 2*64*20 + 16*64 + 16*64 + 256 + 128 + 16 + 4
#define SMEM_FLOATS (256*W2S + 2*16*X2S + 2*64*XTS + 1024 + 1024 + 256 + 128 + 16 + 4)
#define SMEM_BYTES  (SMEM_FLOATS*4)

__global__ __launch_bounds__(256, 1)
void ttt_m2(const float* __restrict__ XQ, const float* __restrict__ XK,
            const float* __restrict__ XV, const float* __restrict__ coeff,
            const float* __restrict__ coeff_last,
            const float* __restrict__ W1g, const float* __restrict__ b1g,
            const float* __restrict__ W2g, const float* __restrict__ b2g,
            const float* __restrict__ gammag, const float* __restrict__ betag,
            float* __restrict__ out)
{
    const int h    = blockIdx.x;    // 0..63  (Bnh)
    const int t    = threadIdx.x;   // 0..255 (column / hf4 index)
    const int lane = t & 63;        // feature index in f=64 phases
    const int w    = t >> 6;        // wave 0..3

    extern __shared__ float smem[];
    float* sW2  = smem;               // [256][68]
    float* sX2  = sW2  + 256*W2S;     // [16][260]
    float* sX2b = sX2  + 16*X2S;      // [16][260]
    float* sxkT = sX2b + 16*X2S;      // [64][20]  xk transposed
    float* sxqT = sxkT + 64*XTS;      // [64][20]
    float* stgt = sxqT + 64*XTS;      // [16][64]  xv - xk
    float* sdZ2 = stgt + 1024;        // [16][64]  Z2 then dZ2 (in place)
    float* sA   = sdZ2 + 1024;        // [16][16]  A1 then A2
    float* sB2  = sA   + 256;         // [2][64]   b2 double buffer
    float* scoef= sB2  + 128;         // [16]
    float* sCL  = scoef+ 16;          // [1]

    // ---------------- init state ----------------
    float w1reg[64];                  // W1 column t (private!)
    #pragma unroll
    for (int k = 0; k < 64; ++k) w1reg[k] = W1g[h*16384 + k*256 + t];
    float b1c = b1g[h*256 + t];

    for (int i = 0; i < 64; ++i) {
        int idx = i*256 + t;          // 16384 floats of W2
        sW2[(idx >> 6)*W2S + (idx & 63)] = W2g[h*16384 + idx];
    }
    if (t < 64) sB2[t] = b2g[h*64 + t];
    const float gj = gammag[(h & 15)*64 + lane];
    const float bj = betag [(h & 15)*64 + lane];

    for (int ci = 0; ci < 128; ++ci) {
        const int cb = ci*65536 + h*1024;

        // ---- P0: stage xk/xq/xv, coeffs ----
        {
            const int k = lane;
            #pragma unroll
            for (int i = 0; i < 4; ++i) {
                const int r = w*4 + i;
                const float xkv = XK[cb + r*64 + k];
                const float xvv = XV[cb + r*64 + k];
                const float xqv = XQ[cb + r*64 + k];
                sxkT[k*XTS + r] = xkv;
                sxqT[k*XTS + r] = xqv;
                stgt[r*64 + k]  = xvv - xkv;
            }
            if (t < 16)  scoef[t] = coeff[ci*1024 + h*16 + t];
            if (t == 16) sCL[0]   = coeff_last[ci*64 + h];
        }
        __syncthreads();

        // ---- PA: Z1 = xk@W1 + b1 ; X2 = gelu(Z1) ; A1 = tril(xq@xk^T)
        float z1[16], x2[16];
        #pragma unroll
        for (int r = 0; r < 16; ++r) z1[r] = b1c;
        #pragma unroll
        for (int k = 0; k < 64; ++k) {
            const float wv = w1reg[k];
            const float4* xr = (const float4*)(sxkT + k*XTS);
            const float4 a = xr[0], b = xr[1], c = xr[2], d = xr[3];
            z1[0]+=a.x*wv;  z1[1]+=a.y*wv;  z1[2]+=a.z*wv;  z1[3]+=a.w*wv;
            z1[4]+=b.x*wv;  z1[5]+=b.y*wv;  z1[6]+=b.z*wv;  z1[7]+=b.w*wv;
            z1[8]+=c.x*wv;  z1[9]+=c.y*wv;  z1[10]+=c.z*wv; z1[11]+=c.w*wv;
            z1[12]+=d.x*wv; z1[13]+=d.y*wv; z1[14]+=d.z*wv; z1[15]+=d.w*wv;
        }
        #pragma unroll
        for (int r = 0; r < 16; ++r) { x2[r] = gelu_f(z1[r]); sX2[r*X2S + t] = x2[r]; }
        {
            const int r = t >> 4, s = t & 15;
            float acc = 0.f;
            #pragma unroll 8
            for (int k = 0; k < 64; ++k)
                acc += sxqT[k*XTS + r] * sxkT[k*XTS + s];
            sA[r*16 + s] = (s <= r) ? acc : 0.0f;
        }
        __syncthreads();

        // ---- PB: Z2 = X2@W2 + b2 -> sdZ2 (holds Z2)
        {
            const float b2v = sB2[(ci & 1)*64 + lane];
            float acc0=b2v, acc1=b2v, acc2=b2v, acc3=b2v;
            const float4* x0 = (const float4*)(sX2 + (w*4+0)*X2S);
            const float4* x1 = (const float4*)(sX2 + (w*4+1)*X2S);
            const float4* x2p= (const float4*)(sX2 + (w*4+2)*X2S);
            const float4* x3 = (const float4*)(sX2 + (w*4+3)*X2S);
            #pragma unroll 4
            for (int p4 = 0; p4 < 64; ++p4) {
                const float4 u0 = x0[p4], u1 = x1[p4], u2 = x2p[p4], u3 = x3[p4];
                const float* wp = sW2 + (4*p4)*W2S + lane;
                const float wa = wp[0], wb = wp[W2S], wc = wp[2*W2S], wd = wp[3*W2S];
                acc0 += u0.x*wa + u0.y*wb + u0.z*wc + u0.w*wd;
                acc1 += u1.x*wa + u1.y*wb + u1.z*wc + u1.w*wd;
                acc2 += u2.x*wa + u2.y*wb + u2.z*wc + u2.w*wd;
                acc3 += u3.x*wa + u3.y*wb + u3.z*wc + u3.w*wd;
            }
            sdZ2[(w*4+0)*64 + lane] = acc0;
            sdZ2[(w*4+1)*64 + lane] = acc1;
            sdZ2[(w*4+2)*64 + lane] = acc2;
            sdZ2[(w*4+3)*64 + lane] = acc3;
        }
        __syncthreads();

        // ---- PC: LN-fused-L2 backward (in place on sdZ2)
        {
            #pragma unroll
            for (int i = 0; i < 4; ++i) {
                const int r = w*4 + i;
                const float z2 = sdZ2[r*64 + lane];
                float s1 = z2, s2 = z2*z2;
                #pragma unroll
                for (int m = 1; m < 64; m <<= 1) {
                    s1 += __shfl_xor(s1, m);
                    s2 += __shfl_xor(s2, m);
                }
                const float mu   = s1*(1.0f/64.0f);
                const float var  = s2*(1.0f/64.0f) - mu*mu;
                const float rstd = rsqrtf(var + 1e-6f);
                const float xh   = (z2 - mu)*rstd;
                const float go   = gj*xh + bj - stgt[r*64 + lane];
                const float g    = go*gj;
                float u1 = g, u2 = g*xh;
                #pragma unroll
                for (int m = 1; m < 64; m <<= 1) {
                    u1 += __shfl_xor(u1, m);
                    u2 += __shfl_xor(u2, m);
                }
                sdZ2[r*64 + lane] = (64.0f*g - u1 - xh*u2)*(rstd*(1.0f/64.0f));
            }
        }
        __syncthreads();

        // ---- PD: dZ1 = (dZ2 @ W2^T) * dgelu(Z1)   (column t, regs)
        float dz1[16];
        #pragma unroll
        for (int r = 0; r < 16; ++r) dz1[r] = 0.f;
        {
            const float4* w2row = (const float4*)(sW2 + t*W2S);
            #pragma unroll 4
            for (int j4 = 0; j4 < 16; ++j4) {
                const float4 wv = w2row[j4];
                #pragma unroll
                for (int r = 0; r < 16; ++r) {
                    const float4 dz = ((const float4*)(sdZ2 + r*64))[j4];
                    dz1[r] += dz.x*wv.x + dz.y*wv.y + dz.z*wv.z + dz.w*wv.w;
                }
            }
            #pragma unroll
            for (int r = 0; r < 16; ++r) dz1[r] *= dgelu_f(z1[r]);
        }

        // ---- PE: xq@W1, b1_bar, A1@dZ1, Z1_bar, X2_bar ; carry b1
        {
            float xqw[16];
            #pragma unroll
            for (int r = 0; r < 16; ++r) xqw[r] = 0.f;
            #pragma unroll
            for (int k = 0; k < 64; ++k) {
                const float wv = w1reg[k];
                const float4* xr = (const float4*)(sxqT + k*XTS);
                const float4 a = xr[0], b = xr[1], c = xr[2], d = xr[3];
                xqw[0]+=a.x*wv;  xqw[1]+=a.y*wv;  xqw[2]+=a.z*wv;  xqw[3]+=a.w*wv;
                xqw[4]+=b.x*wv;  xqw[5]+=b.y*wv;  xqw[6]+=b.z*wv;  xqw[7]+=b.w*wv;
                xqw[8]+=c.x*wv;  xqw[9]+=c.y*wv;  xqw[10]+=c.z*wv; xqw[11]+=c.w*wv;
                xqw[12]+=d.x*wv; xqw[13]+=d.y*wv; xqw[14]+=d.z*wv; xqw[15]+=d.w*wv;
            }
            float cum = 0.f;
            #pragma unroll
            for (int r = 0; r < 16; ++r) {
                cum += dz1[r];
                const float cr = scoef[r];
                const float b1bar = b1c - cr*cum;
                float ad = 0.f;
                #pragma unroll
                for (int s = 0; s <= r; ++s) ad += sA[r*16 + s]*dz1[s];
                const float z1b = xqw[r] - cr*ad + b1bar;
                sX2b[r*X2S + t] = gelu_f(z1b);
                if (r == 15) b1c = b1bar;
            }
        }
        // ---- PG: W1 -= cl * xk^T @ dZ1  (regs only)
        {
            const float clv = sCL[0];
            #pragma unroll
            for (int k = 0; k < 64; ++k) {
                const float4* xr = (const float4*)(sxkT + k*XTS);
                const float4 a = xr[0], b = xr[1], c = xr[2], d = xr[3];
                const float acc = a.x*dz1[0] + a.y*dz1[1] + a.z*dz1[2] + a.w*dz1[3]
                                + b.x*dz1[4] + b.y*dz1[5] + b.z*dz1[6] + b.w*dz1[7]
                                + c.x*dz1[8] + c.y*dz1[9] + c.z*dz1[10]+ c.w*dz1[11]
                                + d.x*dz1[12]+ d.y*dz1[13]+ d.z*dz1[14]+ d.w*dz1[15];
                w1reg[k] -= clv*acc;
            }
        }
        __syncthreads();

        // ---- PF1: A2 = tril(X2_bar @ X2^T)
        {
            const int r = t >> 4, s = t & 15;
            const float4* xb = (const float4*)(sX2b + r*X2S);
            const float4* xa = (const float4*)(sX2  + s*X2S);
            float acc = 0.f;
            #pragma unroll 8
            for (int p4 = 0; p4 < 64; ++p4) {
                const float4 uu = xb[p4], vv = xa[p4];
                acc += uu.x*vv.x + uu.y*vv.y + uu.z*vv.z + uu.w*vv.w;
            }
            sA[r*16 + s] = (s <= r) ? acc : 0.0f;
        }
        __syncthreads();

        // ---- PF2: Z2_bar = X2b@W2 - c*(A2@dZ2) + b2_bar ; write out ; carry b2
        {
            float dz2c[16];
            #pragma unroll
            for (int r = 0; r < 16; ++r) dz2c[r] = sdZ2[r*64 + lane];
            const float b2v = sB2[(ci & 1)*64 + lane];
            float acc[4] = {0.f, 0.f, 0.f, 0.f};
            const float4* x0 = (const float4*)(sX2b + (w*4+0)*X2S);
            const float4* x1 = (const float4*)(sX2b + (w*4+1)*X2S);
            const float4* x2p= (const float4*)(sX2b + (w*4+2)*X2S);
            const float4* x3 = (const float4*)(sX2b + (w*4+3)*X2S);
            #pragma unroll 4
            for (int p4 = 0; p4 < 64; ++p4) {
                const float4 u0 = x0[p4], u1 = x1[p4], u2 = x2p[p4], u3 = x3[p4];
                const float* wp = sW2 + (4*p4)*W2S + lane;
                const float wa = wp[0], wb = wp[W2S], wc = wp[2*W2S], wd = wp[3*W2S];
                acc[0] += u0.x*wa + u0.y*wb + u0.z*wc + u0.w*wd;
                acc[1] += u1.x*wa + u1.y*wb + u1.z*wc + u1.w*wd;
                acc[2] += u2.x*wa + u2.y*wb + u2.z*wc + u2.w*wd;
                acc[3] += u3.x*wa + u3.y*wb + u3.z*wc + u3.w*wd;
            }
            #pragma unroll
            for (int i = 0; i < 4; ++i) {
                const int r = w*4 + i;
                const float cr = scoef[r];
                float ad = 0.f, pf = 0.f;
                #pragma unroll
                for (int s = 0; s < 16; ++s) {
                    const bool m = (s <= r);
                    ad += (m ? sA[r*16 + s] : 0.0f)*dz2c[s];
                    pf += m ? dz2c[s] : 0.0f;
                }
                const float b2bar = b2v - cr*pf;
                out[h*131072 + (ci*16 + r)*64 + lane] = acc[i] - cr*ad + b2bar;
                if (w == 3 && i == 3) sB2[((ci+1)&1)*64 + lane] = b2bar;
            }
        }
        __syncthreads();

        // ---- PH: W2 -= cl * X2^T @ dZ2  (row t of sW2)
        {
            const float clv = sCL[0];
            float4* w2row = (float4*)(sW2 + t*W2S);
            #pragma unroll 4
            for (int j4 = 0; j4 < 16; ++j4) {
                float ax=0.f, ay=0.f, az=0.f, aw=0.f;
                #pragma unroll
                for (int r = 0; r < 16; ++r) {
                    const float4 dz = ((const float4*)(sdZ2 + r*64))[j4];
                    ax += x2[r]*dz.x; ay += x2[r]*dz.y;
                    az += x2[r]*dz.z; aw += x2[r]*dz.w;
                }
                float4 wv = w2row[j4];
                wv.x -= clv*ax; wv.y -= clv*ay; wv.z -= clv*az; wv.w -= clv*aw;
                w2row[j4] = wv;
            }
        }
        __syncthreads();
    }
}

extern "C" void kernel_launch(void* const* d_in, const int* in_sizes, int n_in,
                              void* d_out, int out_size, void* d_ws, size_t ws_size,
                              hipStream_t stream) {
    const float* XQ  = (const float*)d_in[0];
    const float* XK  = (const float*)d_in[1];
    const float* XV  = (const float*)d_in[2];
    const float* cf  = (const float*)d_in[3];
    const float* cfl = (const float*)d_in[4];
    const float* W1  = (const float*)d_in[5];
    const float* b1  = (const float*)d_in[6];
    const float* W2  = (const float*)d_in[7];
    const float* b2  = (const float*)d_in[8];
    const float* gam = (const float*)d_in[9];
    const float* bet = (const float*)d_in[10];
    float* o = (float*)d_out;

    hipFuncSetAttribute((const void*)ttt_m2,
                        hipFuncAttributeMaxDynamicSharedMemorySize, SMEM_BYTES);
    ttt_m2<<<64, 256, SMEM_BYTES, stream>>>(XQ, XK, XV, cf, cfl, W1, b1, W2, b2, gam, bet, o);
}

// Round 2
// 5257.898 us; speedup vs baseline: 3.1553x; 3.1553x over previous
//
#include <hip/hip_runtime.h>

#define A_GELU 0.7978845608028654f
#define W2S  68    // sW2  [256][68]
#define X2S  260   // sX2/sX2b [16][260]
#define XTS  20    // sxkT/sxqT [64][20]
#define DZ1S 258   // sdZ1 [16][258]
#define DZ2S 68    // sdZ2 [16][68]

__device__ __forceinline__ float fast_tanh(float u){
    float e = __expf(2.0f*u);
    return 1.0f - 2.0f/(e + 1.0f);
}
__device__ __forceinline__ float gelu_f(float x){
    float t = fast_tanh(A_GELU*(x + 0.044715f*x*x*x));
    return 0.5f*x*(1.0f+t);
}
__device__ __forceinline__ float dgelu_f(float x){
    float x2 = x*x;
    float t = fast_tanh(A_GELU*x*(1.0f + 0.044715f*x2));
    return 0.5f*x*((1.0f-t*t)*(A_GELU + 0.1070322243f*x2)) + 0.5f*(1.0f+t);
}

// floats: 17408 + 4160 + 4160 + 1280 + 1280 + 1024 + 1088 + 4128 + 256 + 128 + 16 + 4 = 34932
#define SMEM_FLOATS (256*W2S + 2*16*X2S + 2*64*XTS + 16*64 + 16*DZ2S + 16*DZ1S + 256 + 128 + 16 + 4)
#define SMEM_BYTES  (SMEM_FLOATS*4)

__global__ __launch_bounds__(512, 1)
void ttt_m2(const float* __restrict__ XQ, const float* __restrict__ XK,
            const float* __restrict__ XV, const float* __restrict__ coeff,
            const float* __restrict__ coeff_last,
            const float* __restrict__ W1g, const float* __restrict__ b1g,
            const float* __restrict__ W2g, const float* __restrict__ b2g,
            const float* __restrict__ gammag, const float* __restrict__ betag,
            float* __restrict__ out)
{
    const int h    = blockIdx.x;     // head 0..63
    const int t    = threadIdx.x;    // 0..511
    const int lane = t & 63;
    const int wv   = t >> 6;         // wave 0..7
    const int c    = t & 255;        // column 0..255
    const int g    = t >> 8;         // 0/1 -> rows [8g, 8g+8)
    const int r2   = wv*2;           // rows r2, r2+1 for row-parallel phases

    extern __shared__ float smem[];
    float* sW2  = smem;                 // [256][68]
    float* sX2  = sW2  + 256*W2S;       // [16][260]
    float* sX2b = sX2  + 16*X2S;        // [16][260]
    float* sxkT = sX2b + 16*X2S;        // [64][20]
    float* sxqT = sxkT + 64*XTS;        // [64][20]
    float* stgt = sxqT + 64*XTS;        // [16][64]
    float* sdZ2 = stgt + 1024;          // [16][68]
    float* sdZ1 = sdZ2 + 16*DZ2S;       // [16][258]
    float* sA   = sdZ1 + 16*DZ1S;       // [16][16]
    float* sB2  = sA   + 256;           // [2][64]
    float* scoef= sB2  + 128;           // [16]
    float* sCL  = scoef+ 16;            // [1]

    // ---- init state (W1 column c duplicated across g) ----
    float w1reg[64];
    #pragma unroll 8
    for (int k = 0; k < 64; ++k) w1reg[k] = W1g[h*16384 + k*256 + c];
    float b1c = b1g[h*256 + c];
    #pragma unroll 4
    for (int i = 0; i < 32; ++i) {
        const int idx = i*512 + t;
        sW2[(idx >> 6)*W2S + (idx & 63)] = W2g[h*16384 + idx];
    }
    if (t < 64) sB2[t] = b2g[h*64 + t];
    const float gj = gammag[(h & 15)*64 + lane];
    const float bj = betag [(h & 15)*64 + lane];

    for (int ci = 0; ci < 128; ++ci) {
        const int cb = ci*65536 + h*1024;

        // ---- P0: stage xk/xq/xv (2 rows per wave), coeffs ----
        #pragma unroll
        for (int i = 0; i < 2; ++i) {
            const int r = r2 + i;
            const float xkv = XK[cb + r*64 + lane];
            const float xqv = XQ[cb + r*64 + lane];
            const float xvv = XV[cb + r*64 + lane];
            sxkT[lane*XTS + r] = xkv;
            sxqT[lane*XTS + r] = xqv;
            stgt[r*64 + lane]  = xvv - xkv;
        }
        if (t < 16)  scoef[t] = coeff[ci*1024 + h*16 + t];
        if (t == 16) sCL[0]   = coeff_last[ci*64 + h];
        __syncthreads();                                   // B1
        const float clv = sCL[0];

        // ---- PA: z1 rows [8g,8g+8) of column c ; X2 ; A1 ----
        float z1[8];
        #pragma unroll
        for (int i = 0; i < 8; ++i) z1[i] = b1c;
        {
            const float4* xk4 = (const float4*)sxkT;       // float4 idx = k*5 + 2g
            #pragma unroll 8
            for (int k = 0; k < 64; ++k) {
                const float wvv = w1reg[k];
                const float4 a = xk4[k*5 + 2*g];
                const float4 b = xk4[k*5 + 2*g + 1];
                z1[0]+=a.x*wvv; z1[1]+=a.y*wvv; z1[2]+=a.z*wvv; z1[3]+=a.w*wvv;
                z1[4]+=b.x*wvv; z1[5]+=b.y*wvv; z1[6]+=b.z*wvv; z1[7]+=b.w*wvv;
            }
        }
        #pragma unroll
        for (int i = 0; i < 8; ++i) sX2[(8*g+i)*X2S + c] = gelu_f(z1[i]);
        if (t < 256) {                                     // A1 = tril(xq@xk^T)
            const int r = t >> 4, s = t & 15;
            float acc = 0.f;
            #pragma unroll 8
            for (int k = 0; k < 64; ++k) acc += sxqT[k*XTS + r]*sxkT[k*XTS + s];
            sA[r*16 + s] = (s <= r) ? acc : 0.0f;
        }
        __syncthreads();                                   // B2

        // ---- PB: Z2 rows r2,r2+1 col lane -> sdZ2 ----
        {
            const float b2v = sB2[(ci & 1)*64 + lane];
            float a0 = b2v, a1 = b2v;
            const float4* x0 = (const float4*)(sX2 + r2*X2S);
            const float4* x1 = (const float4*)(sX2 + (r2+1)*X2S);
            #pragma unroll 4
            for (int p4 = 0; p4 < 64; ++p4) {
                const float4 u0 = x0[p4], u1 = x1[p4];
                const float* wp = sW2 + (4*p4)*W2S + lane;
                const float wa = wp[0], wb = wp[W2S], wc2 = wp[2*W2S], wd = wp[3*W2S];
                a0 += u0.x*wa + u0.y*wb + u0.z*wc2 + u0.w*wd;
                a1 += u1.x*wa + u1.y*wb + u1.z*wc2 + u1.w*wd;
            }
            sdZ2[r2*DZ2S + lane]     = a0;
            sdZ2[(r2+1)*DZ2S + lane] = a1;
        }
        __syncthreads();                                   // B3

        // ---- PC: LN-fused-L2 backward, in place on sdZ2 ----
        #pragma unroll
        for (int i = 0; i < 2; ++i) {
            const int r = r2 + i;
            const float z2 = sdZ2[r*DZ2S + lane];
            float s1 = z2, s2 = z2*z2;
            #pragma unroll
            for (int m = 1; m < 64; m <<= 1) { s1 += __shfl_xor(s1, m); s2 += __shfl_xor(s2, m); }
            const float mu   = s1*(1.0f/64.0f);
            const float var  = s2*(1.0f/64.0f) - mu*mu;
            const float rstd = rsqrtf(var + 1e-6f);
            const float xh   = (z2 - mu)*rstd;
            const float go   = gj*xh + bj - stgt[r*64 + lane];
            const float gg   = go*gj;
            float u1 = gg, u2 = gg*xh;
            #pragma unroll
            for (int m = 1; m < 64; m <<= 1) { u1 += __shfl_xor(u1, m); u2 += __shfl_xor(u2, m); }
            sdZ2[r*DZ2S + lane] = (64.0f*gg - u1 - xh*u2)*(rstd*(1.0f/64.0f));
        }
        __syncthreads();                                   // B4

        // ---- PD: dz1 rows [8g,8g+8) col c ; stage to sdZ1 ----
        float dz1[8];
        #pragma unroll
        for (int i = 0; i < 8; ++i) dz1[i] = 0.f;
        {
            const float4* w2row = (const float4*)(sW2 + c*W2S);
            #pragma unroll 2
            for (int j4 = 0; j4 < 16; ++j4) {
                const float4 wq = w2row[j4];
                #pragma unroll
                for (int i = 0; i < 8; ++i) {
                    const float4 dq = ((const float4*)(sdZ2 + (8*g+i)*DZ2S))[j4];
                    dz1[i] += dq.x*wq.x + dq.y*wq.y + dq.z*wq.z + dq.w*wq.w;
                }
            }
            #pragma unroll
            for (int i = 0; i < 8; ++i) {
                dz1[i] *= dgelu_f(z1[i]);
                sdZ1[(8*g+i)*DZ1S + c] = dz1[i];
            }
        }
        __syncthreads();                                   // B5

        // ---- PE: xq@W1, b1_bar, A1@dZ1, X2_bar ; PG: W1 update ----
        {
            float xqw[8];
            #pragma unroll
            for (int i = 0; i < 8; ++i) xqw[i] = 0.f;
            const float4* xq4 = (const float4*)sxqT;
            #pragma unroll 8
            for (int k = 0; k < 64; ++k) {
                const float wvv = w1reg[k];
                const float4 a = xq4[k*5 + 2*g];
                const float4 b = xq4[k*5 + 2*g + 1];
                xqw[0]+=a.x*wvv; xqw[1]+=a.y*wvv; xqw[2]+=a.z*wvv; xqw[3]+=a.w*wvv;
                xqw[4]+=b.x*wvv; xqw[5]+=b.y*wvv; xqw[6]+=b.z*wvv; xqw[7]+=b.w*wvv;
            }
            float dzc[16];
            #pragma unroll
            for (int s = 0; s < 16; ++s) dzc[s] = sdZ1[s*DZ1S + c];
            float cum = 0.f;
            #pragma unroll
            for (int r = 0; r < 16; ++r) {
                cum += dzc[r];
                const int i = r - 8*g;                     // wave-uniform branch
                if (i >= 0 && i < 8) {
                    const float cr = scoef[r];
                    float ad = 0.f;
                    #pragma unroll
                    for (int s = 0; s <= r; ++s) ad += sA[r*16 + s]*dzc[s];
                    const float z1b = xqw[i] - cr*ad + (b1c - cr*cum);
                    sX2b[r*X2S + c] = gelu_f(z1b);
                }
            }
            b1c -= scoef[15]*cum;
            // PG: W1 -= cl * xk^T @ dZ1 (duplicated across g)
            const float4* xk4 = (const float4*)sxkT;
            #pragma unroll 4
            for (int k = 0; k < 64; ++k) {
                const float4 a = xk4[k*5], b = xk4[k*5+1], cc = xk4[k*5+2], d = xk4[k*5+3];
                const float acc = a.x*dzc[0] + a.y*dzc[1] + a.z*dzc[2] + a.w*dzc[3]
                                + b.x*dzc[4] + b.y*dzc[5] + b.z*dzc[6] + b.w*dzc[7]
                                + cc.x*dzc[8]+ cc.y*dzc[9]+ cc.z*dzc[10]+cc.w*dzc[11]
                                + d.x*dzc[12]+ d.y*dzc[13]+ d.z*dzc[14]+ d.w*dzc[15];
                w1reg[k] -= clv*acc;
            }
        }
        __syncthreads();                                   // B6

        // ---- PF1: A2 = tril(X2_bar @ X2^T) ----
        if (t < 256) {
            const int r = t >> 4, s = t & 15;
            const float4* xb = (const float4*)(sX2b + r*X2S);
            const float4* xa = (const float4*)(sX2  + s*X2S);
            float acc = 0.f;
            #pragma unroll 8
            for (int p4 = 0; p4 < 64; ++p4) {
                const float4 uu = xb[p4], vvv = xa[p4];
                acc += uu.x*vvv.x + uu.y*vvv.y + uu.z*vvv.z + uu.w*vvv.w;
            }
            sA[r*16 + s] = (s <= r) ? acc : 0.0f;
        }
        __syncthreads();                                   // B7

        // ---- PF2: Z2_bar rows r2,r2+1 ; write out ; carry b2 ----
        {
            float dz2c[16];
            #pragma unroll
            for (int s = 0; s < 16; ++s) dz2c[s] = sdZ2[s*DZ2S + lane];
            const float b2v = sB2[(ci & 1)*64 + lane];
            float a0 = 0.f, a1 = 0.f;
            const float4* x0 = (const float4*)(sX2b + r2*X2S);
            const float4* x1 = (const float4*)(sX2b + (r2+1)*X2S);
            #pragma unroll 4
            for (int p4 = 0; p4 < 64; ++p4) {
                const float4 u0 = x0[p4], u1 = x1[p4];
                const float* wp = sW2 + (4*p4)*W2S + lane;
                const float wa = wp[0], wb = wp[W2S], wc2 = wp[2*W2S], wd = wp[3*W2S];
                a0 += u0.x*wa + u0.y*wb + u0.z*wc2 + u0.w*wd;
                a1 += u1.x*wa + u1.y*wb + u1.z*wc2 + u1.w*wd;
            }
            #pragma unroll
            for (int i = 0; i < 2; ++i) {
                const int r = r2 + i;
                const float cr = scoef[r];
                float ad = 0.f, pf = 0.f;
                #pragma unroll
                for (int s = 0; s < 16; ++s) {
                    const bool m = (s <= r);
                    ad += (m ? sA[r*16 + s] : 0.0f)*dz2c[s];
                    pf += m ? dz2c[s] : 0.0f;
                }
                const float b2bar = b2v - cr*pf;
                out[h*131072 + (ci*16 + r)*64 + lane] = (i == 0 ? a0 : a1) - cr*ad + b2bar;
                if (r == 15) sB2[((ci+1)&1)*64 + lane] = b2bar;
            }
        }
        __syncthreads();                                   // B8

        // ---- PH: W2 update, row c, cols [32g,32g+32) ----
        {
            float x2c[16];
            #pragma unroll
            for (int r = 0; r < 16; ++r) x2c[r] = sX2[r*X2S + c];
            float4* wrow = (float4*)(sW2 + c*W2S + 32*g);
            #pragma unroll 2
            for (int q4 = 0; q4 < 8; ++q4) {
                float ax = 0.f, ay = 0.f, az = 0.f, aw = 0.f;
                #pragma unroll
                for (int r = 0; r < 16; ++r) {
                    const float4 dq = ((const float4*)(sdZ2 + r*DZ2S + 32*g))[q4];
                    ax += x2c[r]*dq.x; ay += x2c[r]*dq.y;
                    az += x2c[r]*dq.z; aw += x2c[r]*dq.w;
                }
                float4 wq = wrow[q4];
                wq.x -= clv*ax; wq.y -= clv*ay; wq.z -= clv*az; wq.w -= clv*aw;
                wrow[q4] = wq;
            }
        }
        // no barrier: next P0 touches only sxkT/sxqT/stgt/scoef/sCL, disjoint
        // from PH's sdZ2/sX2 reads and sW2 writes; B1 orders everything else.
    }
}

extern "C" void kernel_launch(void* const* d_in, const int* in_sizes, int n_in,
                              void* d_out, int out_size, void* d_ws, size_t ws_size,
                              hipStream_t stream) {
    const float* XQ  = (const float*)d_in[0];
    const float* XK  = (const float*)d_in[1];
    const float* XV  = (const float*)d_in[2];
    const float* cf  = (const float*)d_in[3];
    const float* cfl = (const float*)d_in[4];
    const float* W1  = (const float*)d_in[5];
    const float* b1  = (const float*)d_in[6];
    const float* W2  = (const float*)d_in[7];
    const float* b2  = (const float*)d_in[8];
    const float* gam = (const float*)d_in[9];
    const float* bet = (const float*)d_in[10];
    float* o = (float*)d_out;

    hipFuncSetAttribute((const void*)ttt_m2,
                        hipFuncAttributeMaxDynamicSharedMemorySize, SMEM_BYTES);
    ttt_m2<<<64, 512, SMEM_BYTES, stream>>>(XQ, XK, XV, cf, cfl, W1, b1, W2, b2, gam, bet, o);
}

// Round 4
// 1040.944 us; speedup vs baseline: 15.9379x; 5.0511x over previous
//
#include <hip/hip_runtime.h>

typedef __attribute__((ext_vector_type(8))) short bf16x8;
typedef __attribute__((ext_vector_type(4))) float f32x4;

#define MFMA16(a,b,c) __builtin_amdgcn_mfma_f32_16x16x32_bf16(a,b,c,0,0,0)
#define A_GELU 0.7978845608028654f

// ---- LDS byte offsets (all 16B aligned) ----
#define OFF_W1B   0u        // ushort[256][72]  W1 mirror, n-major: [n][m] = W1[m][n]
#define OFF_W2F   36864u    // ushort[64][264]  W2 mirror, f-major: [f][hf] = W2[hf][f]
#define OFF_XK    70656u    // ushort[16][72]   xk row-major bf16
#define OFF_XQ    72960u    // ushort[16][72]
#define OFF_X2    75264u    // ushort[16][264]  X2 row-major
#define OFF_X2B   83712u    // ushort[16][264]  X2_bar row-major
#define OFF_DZ2B  92160u    // ushort[16][72]   dZ2 row-major
#define OFF_DZ1CT 94464u    // ushort[256][40]  dZ1 col-major [n][k-row], k 16..31 zero
#define OFF_DZ2CT 114944u   // ushort[64][40]   dZ2 col-major [n][k-row], k 16..31 zero
#define OFF_M1    120064u   // ushort[16][40]   M1' [r][s], s 16..31 zero
#define OFF_M2    121344u   // ushort[16][40]
#define OFF_Z2F   122624u   // float[16][68]
#define OFF_TGT   126976u   // float[16][64]
#define OFF_B2    131072u   // float[2][64]
#define OFF_COEF  131584u   // float[16]
#define OFF_CL    131648u   // float[1] (+pad)
#define SMEM_BYTES 131712u

__device__ __forceinline__ float fast_tanh(float u){
    float e = __expf(2.0f*u);
    return 1.0f - 2.0f/(e + 1.0f);
}
__device__ __forceinline__ float gelu_f(float x){
    float t = fast_tanh(A_GELU*(x + 0.044715f*x*x*x));
    return 0.5f*x*(1.0f+t);
}
__device__ __forceinline__ float dgelu_f(float x){
    float x2 = x*x;
    float t = fast_tanh(A_GELU*x*(1.0f + 0.044715f*x2));
    return 0.5f*x*((1.0f-t*t)*(A_GELU + 0.1070322243f*x2)) + 0.5f*(1.0f+t);
}
__device__ __forceinline__ short f2bf(float f){
    unsigned u = __builtin_bit_cast(unsigned, f);
    u += 0x7FFFu + ((u >> 16) & 1u);
    return (short)(u >> 16);
}
__device__ __forceinline__ float bf2f(unsigned short s){
    unsigned u = ((unsigned)s) << 16;
    return __builtin_bit_cast(float, u);
}
__device__ __forceinline__ bf16x8 ldfrag(const unsigned short* p){
    return *(const bf16x8*)p;
}

__global__ __launch_bounds__(512, 1)
void ttt_m2(const float* __restrict__ XQ, const float* __restrict__ XK,
            const float* __restrict__ XV, const float* __restrict__ coeff,
            const float* __restrict__ coeff_last,
            const float* __restrict__ W1g, const float* __restrict__ b1g,
            const float* __restrict__ W2g, const float* __restrict__ b2g,
            const float* __restrict__ gammag, const float* __restrict__ betag,
            float* __restrict__ out)
{
    const int h  = blockIdx.x;      // head 0..63
    const int t  = threadIdx.x;     // 0..511
    const int l  = t & 63;          // lane
    const int w  = t >> 6;          // wave 0..7
    const int lo = l & 15;
    const int hi = l >> 4;          // 0..3

    extern __shared__ char smem[];
    unsigned short* sW1bu  = (unsigned short*)(smem + OFF_W1B);
    unsigned short* sW2fu  = (unsigned short*)(smem + OFF_W2F);
    unsigned short* sxku   = (unsigned short*)(smem + OFF_XK);
    unsigned short* sxqu   = (unsigned short*)(smem + OFF_XQ);
    unsigned short* sX2u   = (unsigned short*)(smem + OFF_X2);
    unsigned short* sX2bu  = (unsigned short*)(smem + OFF_X2B);
    unsigned short* sdZ2bu = (unsigned short*)(smem + OFF_DZ2B);
    unsigned short* sdZ1ct = (unsigned short*)(smem + OFF_DZ1CT);
    unsigned short* sdZ2ct = (unsigned short*)(smem + OFF_DZ2CT);
    unsigned short* sM1u   = (unsigned short*)(smem + OFF_M1);
    unsigned short* sM2u   = (unsigned short*)(smem + OFF_M2);
    float* sZ2f  = (float*)(smem + OFF_Z2F);
    float* stgt  = (float*)(smem + OFF_TGT);
    float* b2f   = (float*)(smem + OFF_B2);
    float* scoef = (float*)(smem + OFF_COEF);
    float* sCL   = (float*)(smem + OFF_CL);

    const int base1 = h*16384;   // W1 [64][256]
    const int base2 = h*16384;   // W2 [256][64]

    // ---------------- init ----------------
    // fp32 masters in D-layout of their update matmuls
    float mW1[4][2][4];   // [mtile][ntile-local(2w+tix)][reg]
    float mW2[2][4][4];   // [mtile-local(2w+mi)][ntile][reg]
    #pragma unroll
    for (int mt = 0; mt < 4; ++mt)
      #pragma unroll
      for (int tix = 0; tix < 2; ++tix)
        #pragma unroll
        for (int reg = 0; reg < 4; ++reg) {
            const int m = mt*16 + hi*4 + reg, n = (2*w + tix)*16 + lo;
            mW1[mt][tix][reg] = W1g[base1 + m*256 + n];
        }
    #pragma unroll
    for (int mi = 0; mi < 2; ++mi)
      #pragma unroll
      for (int nt = 0; nt < 4; ++nt)
        #pragma unroll
        for (int reg = 0; reg < 4; ++reg) {
            const int m = (2*w + mi)*16 + hi*4 + reg, n = nt*16 + lo;
            mW2[mi][nt][reg] = W2g[base2 + m*64 + n];
        }
    float b1reg[2];
    b1reg[0] = b1g[h*256 + (2*w)*16 + lo];
    b1reg[1] = b1g[h*256 + (2*w+1)*16 + lo];

    // bf16 mirrors (cooperative)
    for (int i = 0; i < 32; ++i) {
        const int idx = i*512 + t;
        const int m = idx >> 8, n = idx & 255;
        sW1bu[n*72 + m] = f2bf(W1g[base1 + idx]);
    }
    for (int i = 0; i < 32; ++i) {
        const int idx = i*512 + t;
        const int hf = idx >> 6, f = idx & 63;
        sW2fu[f*264 + hf] = f2bf(W2g[base2 + idx]);
    }
    if (t < 64) b2f[t] = b2g[h*64 + t];
    // zero k-pads (16..39) once; only k<16 ever rewritten
    if (t < 256) {
        for (int k = 16; k < 40; ++k) sdZ1ct[t*40 + k] = 0;
    }
    if (t < 64) {
        for (int k = 16; k < 40; ++k) sdZ2ct[t*40 + k] = 0;
    }
    if (t < 16) {
        for (int k = 16; k < 40; ++k) { sM1u[t*40 + k] = 0; sM2u[t*40 + k] = 0; }
    }

    const float gj = gammag[(h & 15)*64 + l];
    const float bj = betag [(h & 15)*64 + l];
    __syncthreads();

    for (int ci = 0; ci < 128; ++ci) {
        const int cb = ci*65536 + h*1024;

        // ---- P0: stage xk/xq bf16, tgt f32, coeffs ----
        #pragma unroll
        for (int i = 0; i < 2; ++i) {
            const int r = w*2 + i;
            const float xkv = XK[cb + r*64 + l];
            const float xqv = XQ[cb + r*64 + l];
            const float xvv = XV[cb + r*64 + l];
            sxku[r*72 + l] = f2bf(xkv);
            sxqu[r*72 + l] = f2bf(xqv);
            stgt[r*64 + l] = xvv - xkv;
        }
        if (t < 16)  scoef[t] = coeff[ci*1024 + h*16 + t];
        if (t == 16) sCL[0]   = coeff_last[ci*64 + h];
        __syncthreads();                                        // B1
        const float clv = sCL[0];
        const float c15 = scoef[15];

        // ---- PA: Z1 = xk@W1 + b1 ; X2 = gelu(Z1) ; wave0: M1' ----
        float z1s[8];
        bf16x8 afk0 = ldfrag(sxku + lo*72 + hi*8);
        bf16x8 afk1 = ldfrag(sxku + lo*72 + 32 + hi*8);
        #pragma unroll
        for (int tix = 0; tix < 2; ++tix) {
            const int n = (2*w + tix)*16 + lo;
            f32x4 acc = {b1reg[tix], b1reg[tix], b1reg[tix], b1reg[tix]};
            acc = MFMA16(afk0, ldfrag(sW1bu + n*72 + hi*8), acc);
            acc = MFMA16(afk1, ldfrag(sW1bu + n*72 + 32 + hi*8), acc);
            #pragma unroll
            for (int reg = 0; reg < 4; ++reg) {
                z1s[tix*4 + reg] = acc[reg];
                sX2u[(hi*4 + reg)*264 + n] = f2bf(gelu_f(acc[reg]));
            }
        }
        if (w == 0) {   // A1 = xq@xk^T ; M1'[r][s] = (s<=r) ? -c_r*(A1+1) : 0
            bf16x8 aq0 = ldfrag(sxqu + lo*72 + hi*8);
            bf16x8 aq1 = ldfrag(sxqu + lo*72 + 32 + hi*8);
            f32x4 a1 = {0.f, 0.f, 0.f, 0.f};
            a1 = MFMA16(aq0, afk0, a1);
            a1 = MFMA16(aq1, afk1, a1);
            #pragma unroll
            for (int reg = 0; reg < 4; ++reg) {
                const int r = hi*4 + reg;
                const float cr = scoef[r];
                const float v = (lo <= r) ? (-cr*(a1[reg] + 1.0f)) : 0.0f;
                sM1u[r*40 + lo] = f2bf(v);
            }
        }
        __syncthreads();                                        // B2

        // ---- PB: Z2 = X2@W2 + b2 (K split across wave-halves) ----
        const int tile = w & 3, kh = w >> 2;
        const int nf = tile*16 + lo;                            // f-col 0..63
        f32x4 accPB;
        if (kh == 0) {
            const float b2v = b2f[(ci & 1)*64 + nf];
            accPB = (f32x4){b2v, b2v, b2v, b2v};
        } else accPB = (f32x4){0.f, 0.f, 0.f, 0.f};
        #pragma unroll
        for (int s = 0; s < 4; ++s) {
            const int k = (kh*4 + s)*32 + hi*8;
            accPB = MFMA16(ldfrag(sX2u + lo*264 + k),
                           ldfrag(sW2fu + nf*264 + k), accPB);
        }
        if (kh == 1) {
            #pragma unroll
            for (int reg = 0; reg < 4; ++reg)
                sZ2f[(hi*4 + reg)*68 + nf] = accPB[reg];
        }
        __syncthreads();                                        // B3
        if (kh == 0) {
            #pragma unroll
            for (int reg = 0; reg < 4; ++reg)
                sZ2f[(hi*4 + reg)*68 + nf] += accPB[reg];
        }
        __syncthreads();                                        // B4

        // ---- PC: LN-fused-L2 backward -> dZ2 (bf16: row-major + col-major) ----
        #pragma unroll
        for (int i = 0; i < 2; ++i) {
            const int r = w*2 + i;
            const float z2 = sZ2f[r*68 + l];
            float s1 = z2, s2 = z2*z2;
            #pragma unroll
            for (int m = 1; m < 64; m <<= 1) { s1 += __shfl_xor(s1, m); s2 += __shfl_xor(s2, m); }
            const float mu   = s1*(1.0f/64.0f);
            const float var  = s2*(1.0f/64.0f) - mu*mu;
            const float rstd = rsqrtf(var + 1e-6f);
            const float xh   = (z2 - mu)*rstd;
            const float go   = gj*xh + bj - stgt[r*64 + l];
            const float gg   = go*gj;
            float u1 = gg, u2 = gg*xh;
            #pragma unroll
            for (int m = 1; m < 64; m <<= 1) { u1 += __shfl_xor(u1, m); u2 += __shfl_xor(u2, m); }
            const float dz2 = (64.0f*gg - u1 - xh*u2)*(rstd*(1.0f/64.0f));
            const short hv = f2bf(dz2);
            sdZ2bu[r*72 + l]  = hv;
            sdZ2ct[l*40 + r]  = hv;
        }
        __syncthreads();                                        // B5

        // ---- PD: dZ1 = (dZ2@W2^T) * dgelu(Z1) -> sdZ1ct ; b1 carry ----
        float b1old[2];
        {
            bf16x8 ad0 = ldfrag(sdZ2bu + lo*72 + hi*8);
            bf16x8 ad1 = ldfrag(sdZ2bu + lo*72 + 32 + hi*8);
            #pragma unroll
            for (int tix = 0; tix < 2; ++tix) {
                const int n = (2*w + tix)*16 + lo;              // hf col
                f32x4 acc = {0.f, 0.f, 0.f, 0.f};
                bf16x8 bw;
                #pragma unroll
                for (int j = 0; j < 8; ++j) bw[j] = (short)sW2fu[(hi*8 + j)*264 + n];
                acc = MFMA16(ad0, bw, acc);
                #pragma unroll
                for (int j = 0; j < 8; ++j) bw[j] = (short)sW2fu[(32 + hi*8 + j)*264 + n];
                acc = MFMA16(ad1, bw, acc);
                float cs = 0.f;
                #pragma unroll
                for (int reg = 0; reg < 4; ++reg) {
                    const int r = hi*4 + reg;
                    const float dz1v = acc[reg]*dgelu_f(z1s[tix*4 + reg]);
                    sdZ1ct[n*40 + r] = f2bf(dz1v);
                    cs += dz1v;
                }
                cs += __shfl_xor(cs, 16);
                cs += __shfl_xor(cs, 32);
                b1old[tix] = b1reg[tix];
                b1reg[tix] -= c15*cs;
            }
        }
        __syncthreads();                                        // B6

        // ---- PE: Z1bar = xq@W1 + b1old + M1'@dZ1 -> X2b ; W1 update ----
        {
            bf16x8 aq0 = ldfrag(sxqu + lo*72 + hi*8);
            bf16x8 aq1 = ldfrag(sxqu + lo*72 + 32 + hi*8);
            bf16x8 am1 = ldfrag(sM1u + lo*40 + hi*8);
            #pragma unroll
            for (int tix = 0; tix < 2; ++tix) {
                const int n = (2*w + tix)*16 + lo;
                f32x4 acc = {b1old[tix], b1old[tix], b1old[tix], b1old[tix]};
                acc = MFMA16(aq0, ldfrag(sW1bu + n*72 + hi*8), acc);
                acc = MFMA16(aq1, ldfrag(sW1bu + n*72 + 32 + hi*8), acc);
                acc = MFMA16(am1, ldfrag(sdZ1ct + n*40 + hi*8), acc);
                #pragma unroll
                for (int reg = 0; reg < 4; ++reg)
                    sX2bu[(hi*4 + reg)*264 + n] = f2bf(gelu_f(acc[reg]));
            }
            // W1 -= cl * xk^T @ dZ1
            bf16x8 bz0 = ldfrag(sdZ1ct + ((2*w)*16 + lo)*40 + hi*8);
            bf16x8 bz1 = ldfrag(sdZ1ct + ((2*w+1)*16 + lo)*40 + hi*8);
            #pragma unroll
            for (int mt = 0; mt < 4; ++mt) {
                bf16x8 axt = (bf16x8){0,0,0,0,0,0,0,0};
                if (l < 32) {
                    #pragma unroll
                    for (int j = 0; j < 8; ++j)
                        axt[j] = (short)sxku[(hi*8 + j)*72 + (mt*16 + lo)];
                }
                f32x4 z4 = {0.f,0.f,0.f,0.f};
                f32x4 u0 = MFMA16(axt, bz0, z4);
                f32x4 u1 = MFMA16(axt, bz1, z4);
                #pragma unroll
                for (int reg = 0; reg < 4; ++reg) {
                    mW1[mt][0][reg] -= clv*u0[reg];
                    mW1[mt][1][reg] -= clv*u1[reg];
                }
            }
        }
        __syncthreads();                                        // B7

        // ---- PF-a: W2 update ; wave0: A2/M2' ; wave1: b2 carry ----
        {
            bf16x8 bz2[4];
            #pragma unroll
            for (int nt = 0; nt < 4; ++nt)
                bz2[nt] = ldfrag(sdZ2ct + (nt*16 + lo)*40 + hi*8);
            #pragma unroll
            for (int mi = 0; mi < 2; ++mi) {
                const int mt = 2*w + mi;
                bf16x8 ax2 = (bf16x8){0,0,0,0,0,0,0,0};
                if (l < 32) {
                    #pragma unroll
                    for (int j = 0; j < 8; ++j)
                        ax2[j] = (short)sX2u[(hi*8 + j)*264 + (mt*16 + lo)];
                }
                #pragma unroll
                for (int nt = 0; nt < 4; ++nt) {
                    f32x4 z4 = {0.f,0.f,0.f,0.f};
                    f32x4 u = MFMA16(ax2, bz2[nt], z4);
                    #pragma unroll
                    for (int reg = 0; reg < 4; ++reg)
                        mW2[mi][nt][reg] -= clv*u[reg];
                }
            }
            if (w == 0) {   // A2 = X2b@X2^T ; M2'
                f32x4 a2 = {0.f,0.f,0.f,0.f};
                #pragma unroll
                for (int ks = 0; ks < 8; ++ks) {
                    const int k = ks*32 + hi*8;
                    a2 = MFMA16(ldfrag(sX2bu + lo*264 + k),
                                ldfrag(sX2u + lo*264 + k), a2);
                }
                #pragma unroll
                for (int reg = 0; reg < 4; ++reg) {
                    const int r = hi*4 + reg;
                    const float cr = scoef[r];
                    const float v = (lo <= r) ? (-cr*(a2[reg] + 1.0f)) : 0.0f;
                    sM2u[r*40 + lo] = f2bf(v);
                }
            }
            if (w == 1) {   // b2 carry: b2_new = b2_old - c15 * colsum(dZ2)
                float cs = 0.f;
                #pragma unroll
                for (int k = 0; k < 16; ++k) cs += bf2f(sdZ2ct[l*40 + k]);
                b2f[((ci+1) & 1)*64 + l] = b2f[(ci & 1)*64 + l] - c15*cs;
            }
        }
        __syncthreads();                                        // B8

        // ---- PF-b: Z2bar = X2b@W2 + b2old + M2'@dZ2 (K split) ----
        f32x4 accPF;
        if (kh == 0) {
            const float b2v = b2f[(ci & 1)*64 + nf];
            accPF = (f32x4){b2v, b2v, b2v, b2v};
        } else accPF = (f32x4){0.f, 0.f, 0.f, 0.f};
        #pragma unroll
        for (int s = 0; s < 4; ++s) {
            const int k = (kh*4 + s)*32 + hi*8;
            accPF = MFMA16(ldfrag(sX2bu + lo*264 + k),
                           ldfrag(sW2fu + nf*264 + k), accPF);
        }
        if (kh == 0) {
            accPF = MFMA16(ldfrag(sM2u + lo*40 + hi*8),
                           ldfrag(sdZ2ct + nf*40 + hi*8), accPF);
        } else {
            #pragma unroll
            for (int reg = 0; reg < 4; ++reg)
                sZ2f[(hi*4 + reg)*68 + nf] = accPF[reg];
        }
        __syncthreads();                                        // B9

        // ---- PF-c: final out (w<4) ; rewrite W1/W2 mirrors ----
        if (kh == 0) {
            #pragma unroll
            for (int reg = 0; reg < 4; ++reg) {
                const int r = hi*4 + reg;
                out[h*131072 + (ci*16 + r)*64 + nf] = accPF[reg] + sZ2f[r*68 + nf];
            }
        }
        #pragma unroll
        for (int mt = 0; mt < 4; ++mt)
          #pragma unroll
          for (int tix = 0; tix < 2; ++tix)
            #pragma unroll
            for (int reg = 0; reg < 4; ++reg) {
                const int m = mt*16 + hi*4 + reg, n = (2*w + tix)*16 + lo;
                sW1bu[n*72 + m] = f2bf(mW1[mt][tix][reg]);
            }
        #pragma unroll
        for (int mi = 0; mi < 2; ++mi)
          #pragma unroll
          for (int nt = 0; nt < 4; ++nt)
            #pragma unroll
            for (int reg = 0; reg < 4; ++reg) {
                const int m = (2*w + mi)*16 + hi*4 + reg, n = nt*16 + lo;
                sW2fu[n*264 + m] = f2bf(mW2[mi][nt][reg]);
            }
        __syncthreads();                                        // B10
    }
}

extern "C" void kernel_launch(void* const* d_in, const int* in_sizes, int n_in,
                              void* d_out, int out_size, void* d_ws, size_t ws_size,
                              hipStream_t stream) {
    const float* XQ  = (const float*)d_in[0];
    const float* XK  = (const float*)d_in[1];
    const float* XV  = (const float*)d_in[2];
    const float* cf  = (const float*)d_in[3];
    const float* cfl = (const float*)d_in[4];
    const float* W1  = (const float*)d_in[5];
    const float* b1  = (const float*)d_in[6];
    const float* W2  = (const float*)d_in[7];
    const float* b2  = (const float*)d_in[8];
    const float* gam = (const float*)d_in[9];
    const float* bet = (const float*)d_in[10];
    float* o = (float*)d_out;

    hipFuncSetAttribute((const void*)ttt_m2,
                        hipFuncAttributeMaxDynamicSharedMemorySize, SMEM_BYTES);
    ttt_m2<<<64, 512, SMEM_BYTES, stream>>>(XQ, XK, XV, cf, cfl, W1, b1, W2, b2, gam, bet, o);
}